// Round 3
// baseline (238.549 us; speedup 1.0000x reference)
//
#include <hip/hip_runtime.h>

// Problem constants (fixed by the reference).
#define BB 4
#define SS 4096
#define DD 2048
#define KK 4
#define D4 (DD / 4)        // 512 float4 channel-groups
#define CHUNK 16           // s-steps per thread
#define NCH (SS / CHUNK)   // 256 chunks per (b, column)
#define NLD (CHUNK + 3)    // 19 float4 loads per thread (3 halo + 16)

// Native clang vector type: __builtin_nontemporal_store requires it.
typedef float f32x4 __attribute__((ext_vector_type(4)));

// y[b,s,d] = bias[d] + sum_{k=0..3} x[b, s-3+k, d] * W[d,k]   (zero-pad s<0)
//
// v3: force the memory-level parallelism the compiler refuses to give us.
// v1/v2 post-mortem: compiler sank all loads to right-before-use
// (VGPR=32!), producing a serial load->wait->fma->store chain per s-step:
// ~2800 cy/memory-op, 2.6 TB/s (32% peak), VALUBusy 3.3%. Source-level
// double-buffering was undone by the scheduler's min-pressure heuristic.
// Fix:
//  - issue ALL 19 independent dwordx4 loads back-to-back, then
//    __builtin_amdgcn_sched_barrier(0): scheduler may not sink loads
//    past it -> 19 KiB in flight per wave. 16 waves/CU x 256 CU ~ 4.9 MB
//    outstanding ~ Little's-law requirement for 6.3 TB/s.
//  - __launch_bounds__(256, 4): budget 128 VGPR so RA keeps 19 float4
//    live (76 VGPR data + ~25 weights/bias/addr) without spilling.
//  - all indexing compile-time (full unroll) so a[] stays in registers.

__device__ __forceinline__ float4 conv4(const float4 bv,
                                        const float4 wr0, const float4 wr1,
                                        const float4 wr2, const float4 wr3,
                                        const float4 xm3, const float4 xm2,
                                        const float4 xm1, const float4 xc) {
  // lane component j (d = 4*d4+j) uses weight row wrj = {W[d,0..3]}
  float4 r;
  r.x = bv.x + wr0.x * xm3.x + wr0.y * xm2.x + wr0.z * xm1.x + wr0.w * xc.x;
  r.y = bv.y + wr1.x * xm3.y + wr1.y * xm2.y + wr1.z * xm1.y + wr1.w * xc.y;
  r.z = bv.z + wr2.x * xm3.z + wr2.y * xm2.z + wr2.z * xm1.z + wr2.w * xc.z;
  r.w = bv.w + wr3.x * xm3.w + wr3.y * xm2.w + wr3.z * xm1.w + wr3.w * xc.w;
  return r;
}

__device__ __forceinline__ void nt_store4(float4* p, const float4 v) {
  f32x4 tmp;
  tmp.x = v.x; tmp.y = v.y; tmp.z = v.z; tmp.w = v.w;
  __builtin_nontemporal_store(tmp, (f32x4*)p);
}

__global__ __launch_bounds__(256, 4) void shortconv_kernel(
    const float4* __restrict__ x,      // (B,S,D) as float4 over D
    const float4* __restrict__ w4,     // (D,4): w4[d] = {W[d,0],W[d,1],W[d,2],W[d,3]}
    const float4* __restrict__ bias4,  // (D/4)
    float4* __restrict__ y)            // (B,S,D) as float4 over D
{
    const int t    = blockIdx.x * 256 + threadIdx.x;
    const int d4   = t & (D4 - 1);
    const int rest = t >> 9;            // / D4
    const int ch   = rest & (NCH - 1);
    const int b    = rest >> 8;         // / NCH

    const int s0 = ch * CHUNK;
    const size_t base = ((size_t)b * SS + (size_t)s0) * D4 + (size_t)d4;

    // ---- phase 1: issue every load, back to back ----------------------
    // a[i] = x[b, s0 - 3 + i, d4]; a[0..2] are the halo.
    float4 a[NLD];
    if (ch == 0) {
        a[0] = make_float4(0.f, 0.f, 0.f, 0.f);
        a[1] = a[0];
        a[2] = a[0];
    } else {
        a[0] = x[base - 3 * (size_t)D4];
        a[1] = x[base - 2 * (size_t)D4];
        a[2] = x[base - 1 * (size_t)D4];
    }
#pragma unroll
    for (int i = 0; i < CHUNK; ++i) {
        a[i + 3] = x[base + (size_t)i * D4];
    }

    // Weights/bias after the bulk loads (they're L2-resident broadcasts;
    // their latency hides under the x loads).
    const float4 wr0 = w4[4 * d4 + 0];
    const float4 wr1 = w4[4 * d4 + 1];
    const float4 wr2 = w4[4 * d4 + 2];
    const float4 wr3 = w4[4 * d4 + 3];
    const float4 bv  = bias4[d4];

    // ---- fence: nothing may cross (keeps all 19 loads hoisted) --------
    __builtin_amdgcn_sched_barrier(0);

    // ---- phase 2: compute + store (waits drain vmcnt progressively) ---
#pragma unroll
    for (int i = 0; i < CHUNK; ++i) {
        const float4 r = conv4(bv, wr0, wr1, wr2, wr3,
                               a[i], a[i + 1], a[i + 2], a[i + 3]);
        nt_store4(&y[base + (size_t)i * D4], r);
    }
}

extern "C" void kernel_launch(void* const* d_in, const int* in_sizes, int n_in,
                              void* d_out, int out_size, void* d_ws, size_t ws_size,
                              hipStream_t stream) {
    const float* x    = (const float*)d_in[0];  // (B,S,D) fp32
    const float* w    = (const float*)d_in[1];  // (D,1,K) fp32
    const float* bias = (const float*)d_in[2];  // (D,)   fp32
    float* out        = (float*)d_out;          // (B,S,D) fp32

    const int total_threads = BB * NCH * D4;    // 524288 = 8192 waves
    const int block = 256;
    const int grid  = total_threads / block;    // 2048

    shortconv_kernel<<<grid, block, 0, stream>>>(
        (const float4*)x, (const float4*)w, (const float4*)bias, (float4*)out);
}

// Round 4
// 231.723 us; speedup vs baseline: 1.0295x; 1.0295x over previous
//
#include <hip/hip_runtime.h>

// Problem constants (fixed by the reference).
#define BB 4
#define SS 4096
#define DD 2048
#define KK 4
#define D4 (DD / 4)        // 512 float4 channel-groups
#define CHUNK 8            // s-steps per block tile
#define NCH (SS / CHUNK)   // 512 chunks per (b, half)
#define ROWS (CHUNK + 3)   // 11 staged rows (3 halo + 8)
#define HALF 256           // float4 channel-groups per block (half of D4)

// Native clang vector type: __builtin_nontemporal_store requires it.
typedef float f32x4 __attribute__((ext_vector_type(4)));

// v4: global_load_lds staging — remove VGPRs from the load path.
//
// Post-mortem v1-v3: every attempt at deep per-wave MLP through registers
// was destroyed by the register allocator (v3: 19 in-flight float4 need
// >=76 VGPRs, RA allocated 56 => spill stores between loads => serial
// load->wait chain; dur pinned at 82us / 2.6 TB/s across all variants).
// Fix: __builtin_amdgcn_global_load_lds(width=16) has NO destination
// register — a wave issues 11 back-to-back 1KiB direct-to-LDS loads with
// zero register pressure. 44 KiB LDS/block => 3 blocks/CU => ~132 KiB
// outstanding per CU during load phases; cross-block overlap (one block
// draining, two computing/storing) replaces per-wave pipelining.
//
// Layout: block = (b, chunk of 8 s-positions, half-row of 256 float4).
// LDS rows are linear; global source is per-lane, LDS dest is
// wave-uniform base + lane*16 (m104 constraint satisfied).
// Compute: sliding 4-row window read from LDS (stride-1 ds_read_b128,
// conflict-free), nontemporal stores (y never re-read; keep x L3-resident).

__device__ __forceinline__ float4 conv4(const float4 bv,
                                        const float4 wr0, const float4 wr1,
                                        const float4 wr2, const float4 wr3,
                                        const float4 xm3, const float4 xm2,
                                        const float4 xm1, const float4 xc) {
  // lane component j (d = 4*d4+j) uses weight row wrj = {W[d,0..3]}
  float4 r;
  r.x = bv.x + wr0.x * xm3.x + wr0.y * xm2.x + wr0.z * xm1.x + wr0.w * xc.x;
  r.y = bv.y + wr1.x * xm3.y + wr1.y * xm2.y + wr1.z * xm1.y + wr1.w * xc.y;
  r.z = bv.z + wr2.x * xm3.z + wr2.y * xm2.z + wr2.z * xm1.z + wr2.w * xc.z;
  r.w = bv.w + wr3.x * xm3.w + wr3.y * xm2.w + wr3.z * xm1.w + wr3.w * xc.w;
  return r;
}

__device__ __forceinline__ void nt_store4(float4* p, const float4 v) {
  f32x4 tmp;
  tmp.x = v.x; tmp.y = v.y; tmp.z = v.z; tmp.w = v.w;
  __builtin_nontemporal_store(tmp, (f32x4*)p);
}

#define GLD_LDS(gp, lp)                                                       \
  __builtin_amdgcn_global_load_lds(                                          \
      (const __attribute__((address_space(1))) void*)(gp),                   \
      (__attribute__((address_space(3))) void*)(lp), 16, 0, 0)

__global__ __launch_bounds__(256) void shortconv_kernel(
    const float4* __restrict__ x,      // (B,S,D) as float4 over D
    const float4* __restrict__ w4,     // (D,4): w4[d] = {W[d,0],W[d,1],W[d,2],W[d,3]}
    const float4* __restrict__ bias4,  // (D/4)
    float4* __restrict__ y)            // (B,S,D) as float4 over D
{
    __shared__ float4 sx[ROWS][HALF];  // 44 KiB

    const int blk  = blockIdx.x;
    const int half = blk & 1;
    const int ch   = (blk >> 1) & (NCH - 1);
    const int b    = blk >> 10;              // / (2*NCH)

    const int ld4  = threadIdx.x;            // 0..255 local channel-group
    const int g_d4 = half * HALF + ld4;      // global channel-group
    const int wave = threadIdx.x >> 6;

    const int s0 = ch * CHUNK;
    const size_t base = ((size_t)b * SS + (size_t)s0) * D4 + (size_t)g_d4;

    // ---- weight/bias loads first: latency hides under the LDS staging ----
    const float4 wr0 = w4[4 * g_d4 + 0];
    const float4 wr1 = w4[4 * g_d4 + 1];
    const float4 wr2 = w4[4 * g_d4 + 2];
    const float4 wr3 = w4[4 * g_d4 + 3];
    const float4 bv  = bias4[g_d4];

    // ---- stage rows s0-3 .. s0+CHUNK-1 into LDS (no VGPR data path) ----
    // Row r holds x[b, s0-3+r, half*1024 .. half*1024+1023].
    if (ch != 0) {
#pragma unroll
        for (int r = 0; r < ROWS; ++r) {
            GLD_LDS(x + base + (size_t)(r - 3) * D4, &sx[r][wave << 6]);
        }
    } else {
        // causal zero-pad: rows 0..2 are s<0
        const float4 z = make_float4(0.f, 0.f, 0.f, 0.f);
        sx[0][ld4] = z;
        sx[1][ld4] = z;
        sx[2][ld4] = z;
#pragma unroll
        for (int r = 3; r < ROWS; ++r) {
            GLD_LDS(x + base + (size_t)(r - 3) * D4, &sx[r][wave << 6]);
        }
    }

    __syncthreads();   // emits s_waitcnt vmcnt(0) lgkmcnt(0) + s_barrier

    // ---- sliding-window compute from LDS + nontemporal stores ----
    float4 x0 = sx[0][ld4];
    float4 x1 = sx[1][ld4];
    float4 x2 = sx[2][ld4];
#pragma unroll
    for (int i = 0; i < CHUNK; ++i) {
        const float4 x3 = sx[i + 3][ld4];
        const float4 r = conv4(bv, wr0, wr1, wr2, wr3, x0, x1, x2, x3);
        nt_store4(&y[base + (size_t)i * D4], r);
        x0 = x1;
        x1 = x2;
        x2 = x3;
    }
}

extern "C" void kernel_launch(void* const* d_in, const int* in_sizes, int n_in,
                              void* d_out, int out_size, void* d_ws, size_t ws_size,
                              hipStream_t stream) {
    const float* x    = (const float*)d_in[0];  // (B,S,D) fp32
    const float* w    = (const float*)d_in[1];  // (D,1,K) fp32
    const float* bias = (const float*)d_in[2];  // (D,)   fp32
    float* out        = (float*)d_out;          // (B,S,D) fp32

    const int grid  = BB * NCH * 2;             // 4096 blocks (one tile each)
    const int block = 256;

    shortconv_kernel<<<grid, block, 0, stream>>>(
        (const float4*)x, (const float4*)w, (const float4*)bias, (float4*)out);
}